// Round 8
// baseline (142.892 us; speedup 1.0000x reference)
//
#include <hip/hip_runtime.h>
#include <hip/hip_bf16.h>
#include <math.h>

// Problem constants (B,F,H,E,O) = (512,512,512,8,512)
enum { Bq = 512, Fq = 512, Hq = 512, Eq = 8, Oq = 512 };

typedef __attribute__((ext_vector_type(8))) short short8;
typedef __attribute__((ext_vector_type(4))) float floatx4;

static __device__ __forceinline__ unsigned short f2bf(float f) {
  unsigned u = __float_as_uint(f);
  u += 0x7fffu + ((u >> 16) & 1u);
  return (unsigned short)(u >> 16);
}
static __device__ __forceinline__ float bf2f(unsigned short h) {
  return __uint_as_float(((unsigned)h) << 16);
}
static __device__ __forceinline__ float elu1(float v) {
  return v > 0.f ? v : (__expf(v) - 1.f);
}

// async global->LDS 16B copy (wave-uniform LDS base + lane*16 scatter)
typedef __attribute__((address_space(1))) const unsigned int gu32;
typedef __attribute__((address_space(3))) unsigned int lu32;
static __device__ __forceinline__ void gld16(const unsigned short* g,
                                             unsigned short* l) {
  __builtin_amdgcn_global_load_lds((gu32*)g, (lu32*)l, 16, 0, 0);
}

// XOR swizzle on 16B chunks (fragment-read conflicts -> 2-way = free).
static __device__ __forceinline__ int swz(int q, int r) {
  return (q & ~7) | ((q ^ r) & 7);
}

// ---------- fp32 -> bf16 convert, 3 big (alpha) + 3 small segments ----------
__global__ __launch_bounds__(256) void cvt6_kernel(
    const float* __restrict__ b0, const float* __restrict__ b1,
    const float* __restrict__ b2, unsigned short* __restrict__ db0,
    unsigned short* __restrict__ db1, unsigned short* __restrict__ db2,
    const float* __restrict__ s0, const float* __restrict__ s1,
    const float* __restrict__ s2, unsigned short* __restrict__ ds0,
    unsigned short* __restrict__ ds1, unsigned short* __restrict__ ds2,
    int nb, int ns) {
  int i = blockIdx.x * 256 + threadIdx.x;
  const float4* s;
  unsigned short* d;
  int j;
  if (i < 3 * nb) {
    int seg = i / nb;
    j = i - seg * nb;
    s = (seg == 0) ? (const float4*)b0
      : (seg == 1) ? (const float4*)b1 : (const float4*)b2;
    d = (seg == 0) ? db0 : (seg == 1) ? db1 : db2;
  } else {
    int k = i - 3 * nb;
    if (k >= 3 * ns) return;
    int seg = k / ns;
    j = k - seg * ns;
    s = (seg == 0) ? (const float4*)s0
      : (seg == 1) ? (const float4*)s1 : (const float4*)s2;
    d = (seg == 0) ? ds0 : (seg == 1) ? ds1 : ds2;
  }
  float4 v = s[j];
  ushort4 o;
  o.x = f2bf(v.x); o.y = f2bf(v.y); o.z = f2bf(v.z); o.w = f2bf(v.w);
  *(ushort4*)(d + 4 * (size_t)j) = o;
}

// ------- gating GEMM: 32x32 tile, BK=512 (full K), ONE barrier/block --------
__global__ __launch_bounds__(256) void gating_gemm(
    const unsigned short* __restrict__ A, const unsigned short* __restrict__ W,
    const float* __restrict__ bias, unsigned short* __restrict__ C) {
  __shared__ unsigned short As[32 * 512];
  __shared__ unsigned short Ws[32 * 512];
  const int tid = threadIdx.x;
  const int wave = tid >> 6, lane = tid & 63;
  const int wm = wave >> 1, wn = wave & 1;
  const int lr = lane & 15, lk = lane >> 4;
  const int m0 = blockIdx.y * 32, n0 = blockIdx.x * 32;
#pragma unroll
  for (int i = 0; i < 8; i++) {
    int c = tid + i * 256;
    int r = c >> 6, ql = c & 63;
    gld16(&A[(size_t)(m0 + r) * 512 + swz(ql, r) * 8], &As[(c & ~63) * 8]);
  }
#pragma unroll
  for (int i = 0; i < 8; i++) {
    int c = tid + i * 256;
    int r = c >> 6, ql = c & 63;
    gld16(&W[(size_t)(n0 + r) * 512 + swz(ql, r) * 8], &Ws[(c & ~63) * 8]);
  }
  __syncthreads();
  const int rA = wm * 16 + lr, rB = wn * 16 + lr;
  floatx4 ac[4];
#pragma unroll
  for (int j = 0; j < 4; j++) ac[j] = (floatx4){0.f, 0.f, 0.f, 0.f};
#pragma unroll
  for (int t = 0; t < 4; t++) {
#pragma unroll
    for (int j = 0; j < 4; j++) {
      int q = ((j * 128 + t * 32) >> 3) + lk;
      short8 av = *(const short8*)&As[rA * 512 + swz(q, rA) * 8];
      short8 bv = *(const short8*)&Ws[rB * 512 + swz(q, rB) * 8];
      ac[j] = __builtin_amdgcn_mfma_f32_16x16x32_bf16(av, bv, ac[j], 0, 0, 0);
    }
  }
  floatx4 acc = (ac[0] + ac[1]) + (ac[2] + ac[3]);
  int n = n0 + wn * 16 + lr;
  float bn = bias[n];
  // C/D layout (m89-verified): col = lane&15, row = (lane>>4)*4 + reg
#pragma unroll
  for (int r = 0; r < 4; r++) {
    int m = m0 + wm * 16 + lk * 4 + r;
    C[(size_t)m * 512 + n] = f2bf(elu1(acc[r] + bn));
  }
}

// ---- expert GEMM v2: BM=BN=64, BK=128, kz=4; e-loop with D=3 W pipeline ----
// grid (8 n, 8 m, 4 kz) = 256 blocks, LDS 66 KB -> 1 block/CU, 4 waves.
// Wave tile 32x32 = 2x2 MFMA tiles; A fragments hoisted to registers once
// (A invariant across experts) -> per-expert LDS reads are B-only.
// Pipeline: raw s_waitcnt vmcnt(4) + s_barrier keeps W[e+1],W[e+2] staging
// in flight across barriers (never vmcnt(0) mid-loop).
template <int FROMP>
__global__ __launch_bounds__(256) void expert_gemm(
    const unsigned short* __restrict__ A,   // [512,512] bf16 (FROMP=0)
    const float* __restrict__ Pin,          // [4][512][512] (FROMP=1)
    const unsigned short* __restrict__ Wb,  // [E*512,512] bf16 alpha bank
    const float* __restrict__ g,            // [512,8] gates
    const float* __restrict__ beta,         // [E*512] fp32
    float* __restrict__ Pout) {             // [4][512][512] fp32 partials
  __shared__ unsigned short As[64 * 128];     // 16 KB
  __shared__ unsigned short Ws[3][64 * 128];  // 3 x 16 KB
  __shared__ float gl[64 * 8];                // 2 KB gates cache
  const int tid = threadIdx.x;
  const int wave = tid >> 6, lane = tid & 63;
  const int wm = wave >> 1, wn = wave & 1;
  const int lr = lane & 15, lk = lane >> 4;
  const int n0 = blockIdx.x * 64, m0 = blockIdx.y * 64;
  const int kz = blockIdx.z, kbeg = kz * 128;

  // ---- A panel staging (64 rows x 128 cols, 16 chunks/row) ----
  if (FROMP) {
#pragma unroll
    for (int i = 0; i < 4; i++) {
      int c = tid + i * 256;
      int r = c >> 4, q = c & 15;
      const float* p = Pin + (size_t)(m0 + r) * 512 + kbeg + q * 8;
      float s0 = 0.f, s1 = 0.f, s2 = 0.f, s3 = 0.f;
      float s4 = 0.f, s5 = 0.f, s6 = 0.f, s7 = 0.f;
#pragma unroll
      for (int z = 0; z < 4; z++) {
        const float* pz = p + (size_t)z * (Bq * Hq);
        float4 a = *(const float4*)pz;
        float4 b = *(const float4*)(pz + 4);
        s0 += a.x; s1 += a.y; s2 += a.z; s3 += a.w;
        s4 += b.x; s5 += b.y; s6 += b.z; s7 += b.w;
      }
      short8 o;
      o[0] = (short)f2bf(elu1(s0)); o[1] = (short)f2bf(elu1(s1));
      o[2] = (short)f2bf(elu1(s2)); o[3] = (short)f2bf(elu1(s3));
      o[4] = (short)f2bf(elu1(s4)); o[5] = (short)f2bf(elu1(s5));
      o[6] = (short)f2bf(elu1(s6)); o[7] = (short)f2bf(elu1(s7));
      *(short8*)&As[(r * 16 + swz(q, r)) * 8] = o;
    }
  } else {
#pragma unroll
    for (int i = 0; i < 4; i++) {
      int c = tid + i * 256;
      int r = c >> 4, ql = c & 15;
      gld16(&A[(size_t)(m0 + r) * 512 + kbeg + swz(ql, r) * 8],
            &As[(c & ~63) * 8]);
    }
  }
  // gates for the block's 64 rows -> LDS (ds_read in-loop keeps the manual
  // vmcnt discipline clean: no global loads inside the e-loop)
  if (tid < 128)
    ((float4*)gl)[tid] = ((const float4*)(g + (size_t)m0 * 8))[tid];

  // issue W panels for experts 0 and 1
  auto stageW = [&](int e, int b) {
    const unsigned short* Wp = Wb + ((size_t)e * 512 + n0) * 512 + kbeg;
#pragma unroll
    for (int i = 0; i < 4; i++) {
      int c = tid + i * 256;
      int r = c >> 4, ql = c & 15;
      gld16(&Wp[(size_t)r * 512 + swz(ql, r) * 8], &Ws[b][(c & ~63) * 8]);
    }
  };
  stageW(0, 0);
  stageW(1, 1);

  const int rA0 = wm * 32 + lr, rB0 = wn * 32 + lr;
  short8 af[2][4];  // A fragments, loaded once after first barrier
  floatx4 fin[2][2];
#pragma unroll
  for (int i = 0; i < 2; i++)
#pragma unroll
    for (int j = 0; j < 2; j++) fin[i][j] = (floatx4){0.f, 0.f, 0.f, 0.f};

#pragma unroll
  for (int e = 0; e < 8; e++) {
    // wait for W[e]'s 4 loads (and, at e=0, A's loads + LDS writes), keeping
    // the newer panel(s) in flight; then barrier.
    if (e == 0)
      __builtin_amdgcn_s_waitcnt(0x0074);  // vmcnt(4) lgkmcnt(0)
    else if (e < 7)
      __builtin_amdgcn_s_waitcnt(0x0F74);  // vmcnt(4)
    else
      __builtin_amdgcn_s_waitcnt(0x0F70);  // vmcnt(0)
    __builtin_amdgcn_s_barrier();
    if (e + 2 < 8) stageW(e + 2, (e + 2) % 3);
    if (e == 0) {
#pragma unroll
      for (int i = 0; i < 2; i++) {
        int r = rA0 + i * 16;
#pragma unroll
        for (int t = 0; t < 4; t++)
          af[i][t] = *(const short8*)&As[r * 128 + swz(t * 4 + lk, r) * 8];
      }
    }
    const unsigned short* wb = Ws[e % 3];
    floatx4 acc[2][2];
#pragma unroll
    for (int i = 0; i < 2; i++)
#pragma unroll
      for (int j = 0; j < 2; j++) acc[i][j] = (floatx4){0.f, 0.f, 0.f, 0.f};
#pragma unroll
    for (int t = 0; t < 4; t++) {
      short8 bf[2];
#pragma unroll
      for (int j = 0; j < 2; j++) {
        int r = rB0 + j * 16;
        bf[j] = *(const short8*)&wb[r * 128 + swz(t * 4 + lk, r) * 8];
      }
#pragma unroll
      for (int i = 0; i < 2; i++)
#pragma unroll
        for (int j = 0; j < 2; j++)
          acc[i][j] = __builtin_amdgcn_mfma_f32_16x16x32_bf16(
              af[i][t], bf[j], acc[i][j], 0, 0, 0);
    }
    // gate-scale into fin (gates via LDS)
#pragma unroll
    for (int i = 0; i < 2; i++) {
#pragma unroll
      for (int r = 0; r < 4; r++) {
        float ge = gl[(wm * 32 + i * 16 + lk * 4 + r) * 8 + e];
#pragma unroll
        for (int j = 0; j < 2; j++) fin[i][j][r] += ge * acc[i][j][r];
      }
    }
  }

  // epilogue: kz==0 folds gate-blended beta; write fp32 partial
  float* Po = Pout + (size_t)kz * Bq * Hq;
#pragma unroll
  for (int i = 0; i < 2; i++) {
#pragma unroll
    for (int j = 0; j < 2; j++) {
      int n = n0 + wn * 32 + j * 16 + lr;
#pragma unroll
      for (int r = 0; r < 4; r++) {
        int m = m0 + wm * 32 + i * 16 + lk * 4 + r;
        float v = fin[i][j][r];
        if (kz == 0) {
#pragma unroll
          for (int e = 0; e < 8; e++)
            v += gl[(wm * 32 + i * 16 + lk * 4 + r) * 8 + e] *
                 beta[e * 512 + n];
        }
        Po[(size_t)m * 512 + n] = v;
      }
    }
  }
}

// ---------------- gate logits + softmax (one wave per sample) ----------------
__global__ __launch_bounds__(64) void gate_kernel(
    const unsigned short* __restrict__ G1,  // [B,H] bf16
    const float* __restrict__ gw2,          // [E,H]
    const float* __restrict__ gb2,          // [E]
    float* __restrict__ g) {                // [B,E]
  int b = blockIdx.x;
  int lane = threadIdx.x;
  float xv[8];
#pragma unroll
  for (int t = 0; t < 8; t++) xv[t] = bf2f(G1[(size_t)b * Hq + t * 64 + lane]);
  float le[Eq];
#pragma unroll
  for (int e = 0; e < Eq; e++) {
    float p = 0.f;
#pragma unroll
    for (int t = 0; t < 8; t++)
      p += xv[t] * gw2[(size_t)e * Hq + t * 64 + lane];
#pragma unroll
    for (int o = 32; o > 0; o >>= 1) p += __shfl_xor(p, o);
    le[e] = p + gb2[e];
  }
  float m = le[0];
#pragma unroll
  for (int e = 1; e < Eq; e++) m = fmaxf(m, le[e]);
  float s = 0.f;
#pragma unroll
  for (int e = 0; e < Eq; e++) {
    le[e] = __expf(le[e] - m);
    s += le[e];
  }
  float inv = 1.f / s;
  if (lane == 0) {
#pragma unroll
    for (int e = 0; e < Eq; e++) g[(size_t)b * Eq + e] = le[e] * inv;
  }
}

// ---------- final reduce: out = sum_z P[z] (beta already folded) ------------
__global__ __launch_bounds__(256) void reduce_final(
    const float* __restrict__ P, float* __restrict__ outf) {
  int idx = blockIdx.x * 256 + threadIdx.x;  // over B*H/4
  float4 s = {0.f, 0.f, 0.f, 0.f};
#pragma unroll
  for (int z = 0; z < 4; z++) {
    float4 v = ((const float4*)(P + (size_t)z * Bq * Hq))[idx];
    s.x += v.x; s.y += v.y; s.z += v.z; s.w += v.w;
  }
  ((float4*)outf)[idx] = s;
}

extern "C" void kernel_launch(void* const* d_in, const int* in_sizes, int n_in,
                              void* d_out, int out_size, void* d_ws,
                              size_t ws_size, hipStream_t stream) {
  const float* x = (const float*)d_in[0];
  const float* gw0 = (const float*)d_in[1];
  const float* gb0 = (const float*)d_in[2];
  const float* gw1 = (const float*)d_in[3];
  const float* gb1 = (const float*)d_in[4];
  const float* gw2 = (const float*)d_in[5];
  const float* gb2 = (const float*)d_in[6];
  const float* alpha0 = (const float*)d_in[7];
  const float* beta0 = (const float*)d_in[8];
  const float* alpha1 = (const float*)d_in[9];
  const float* beta1 = (const float*)d_in[10];
  const float* alpha2 = (const float*)d_in[11];
  const float* beta2 = (const float*)d_in[12];
  float* out = (float*)d_out;

  char* ws = (char*)d_ws;
  auto alloc = [&](size_t bytes) {
    char* p = ws;
    ws += (bytes + 255) & ~(size_t)255;
    return p;
  };
  unsigned short* xb = (unsigned short*)alloc((size_t)Bq * Fq * 2);
  unsigned short* gw0b = (unsigned short*)alloc((size_t)Hq * Fq * 2);
  unsigned short* gw1b = (unsigned short*)alloc((size_t)Hq * Hq * 2);
  unsigned short* a0b = (unsigned short*)alloc((size_t)Eq * Hq * Fq * 2);
  unsigned short* a1b = (unsigned short*)alloc((size_t)Eq * Hq * Hq * 2);
  unsigned short* a2b = (unsigned short*)alloc((size_t)Eq * Oq * Hq * 2);
  unsigned short* G0b = (unsigned short*)alloc((size_t)Bq * Hq * 2);
  unsigned short* G1b = (unsigned short*)alloc((size_t)Bq * Hq * 2);
  float* gates = (float*)alloc((size_t)Bq * Eq * 4);
  float* P1 = (float*)alloc((size_t)4 * Bq * Hq * 4);
  float* P2 = (float*)alloc((size_t)4 * Bq * Hq * 4);

  // 1) all fp32->bf16 converts in one launch
  {
    int nb = (Eq * Hq * Fq) / 4, ns = (Bq * Fq) / 4;
    int total = 3 * nb + 3 * ns;
    cvt6_kernel<<<(total + 255) / 256, 256, 0, stream>>>(
        alpha0, alpha1, alpha2, a0b, a1b, a2b, x, gw0, gw1, xb, gw0b, gw1b,
        nb, ns);
  }

  // 2) gating MLP: single-barrier 32x32 tiles, 256 blocks each
  dim3 gg(16, 16);
  gating_gemm<<<gg, 256, 0, stream>>>(xb, gw0b, gb0, G0b);
  gating_gemm<<<gg, 256, 0, stream>>>(G0b, gw1b, gb1, G1b);

  // 3) gate logits + softmax
  gate_kernel<<<Bq, 64, 0, stream>>>(G1b, gw2, gb2, gates);

  // 4) experts: pipelined all-8-expert blocks, kz=4 partials; final reduce
  dim3 ge(8, 8, 4);
  expert_gemm<0><<<ge, 256, 0, stream>>>(xb, nullptr, a0b, gates, beta0, P1);
  expert_gemm<1><<<ge, 256, 0, stream>>>(nullptr, P1, a1b, gates, beta1, P2);
  expert_gemm<1><<<ge, 256, 0, stream>>>(nullptr, P2, a2b, gates, beta2, P1);
  reduce_final<<<(Bq * Hq / 4) / 256, 256, 0, stream>>>(P1, out);
}

// Round 9
// 139.158 us; speedup vs baseline: 1.0268x; 1.0268x over previous
//
#include <hip/hip_runtime.h>
#include <hip/hip_bf16.h>
#include <math.h>

// Problem constants (B,F,H,E,O) = (512,512,512,8,512)
enum { Bq = 512, Fq = 512, Hq = 512, Eq = 8, Oq = 512 };

typedef __attribute__((ext_vector_type(8))) short short8;
typedef __attribute__((ext_vector_type(4))) float floatx4;

static __device__ __forceinline__ unsigned short f2bf(float f) {
  unsigned u = __float_as_uint(f);
  u += 0x7fffu + ((u >> 16) & 1u);
  return (unsigned short)(u >> 16);
}
static __device__ __forceinline__ float bf2f(unsigned short h) {
  return __uint_as_float(((unsigned)h) << 16);
}
static __device__ __forceinline__ float elu1(float v) {
  return v > 0.f ? v : (__expf(v) - 1.f);
}

// async global->LDS 16B copy (wave-uniform LDS base + lane*16 scatter)
typedef __attribute__((address_space(1))) const unsigned int gu32;
typedef __attribute__((address_space(3))) unsigned int lu32;
static __device__ __forceinline__ void gld16(const unsigned short* g,
                                             unsigned short* l) {
  __builtin_amdgcn_global_load_lds((gu32*)g, (lu32*)l, 16, 0, 0);
}

// XOR swizzle on 16B chunks (fragment-read conflicts -> 2-way = free).
static __device__ __forceinline__ int swz(int q, int r) {
  return (q & ~7) | ((q ^ r) & 7);
}

// ---------- fp32 -> bf16 convert, 3 big (alpha) + 3 small segments ----------
__global__ __launch_bounds__(256) void cvt6_kernel(
    const float* __restrict__ b0, const float* __restrict__ b1,
    const float* __restrict__ b2, unsigned short* __restrict__ db0,
    unsigned short* __restrict__ db1, unsigned short* __restrict__ db2,
    const float* __restrict__ s0, const float* __restrict__ s1,
    const float* __restrict__ s2, unsigned short* __restrict__ ds0,
    unsigned short* __restrict__ ds1, unsigned short* __restrict__ ds2,
    int nb, int ns) {
  int i = blockIdx.x * 256 + threadIdx.x;
  const float4* s;
  unsigned short* d;
  int j;
  if (i < 3 * nb) {
    int seg = i / nb;
    j = i - seg * nb;
    s = (seg == 0) ? (const float4*)b0
      : (seg == 1) ? (const float4*)b1 : (const float4*)b2;
    d = (seg == 0) ? db0 : (seg == 1) ? db1 : db2;
  } else {
    int k = i - 3 * nb;
    if (k >= 3 * ns) return;
    int seg = k / ns;
    j = k - seg * ns;
    s = (seg == 0) ? (const float4*)s0
      : (seg == 1) ? (const float4*)s1 : (const float4*)s2;
    d = (seg == 0) ? ds0 : (seg == 1) ? ds1 : ds2;
  }
  float4 v = s[j];
  ushort4 o;
  o.x = f2bf(v.x); o.y = f2bf(v.y); o.z = f2bf(v.z); o.w = f2bf(v.w);
  *(ushort4*)(d + 4 * (size_t)j) = o;
}

// ------- gating GEMM: 32x32 tile, BK=512 (full K), ONE barrier/block --------
__global__ __launch_bounds__(256) void gating_gemm(
    const unsigned short* __restrict__ A, const unsigned short* __restrict__ W,
    const float* __restrict__ bias, unsigned short* __restrict__ C) {
  __shared__ unsigned short As[32 * 512];
  __shared__ unsigned short Ws[32 * 512];
  const int tid = threadIdx.x;
  const int wave = tid >> 6, lane = tid & 63;
  const int wm = wave >> 1, wn = wave & 1;
  const int lr = lane & 15, lk = lane >> 4;
  const int m0 = blockIdx.y * 32, n0 = blockIdx.x * 32;
#pragma unroll
  for (int i = 0; i < 8; i++) {
    int c = tid + i * 256;
    int r = c >> 6, ql = c & 63;
    gld16(&A[(size_t)(m0 + r) * 512 + swz(ql, r) * 8], &As[(c & ~63) * 8]);
  }
#pragma unroll
  for (int i = 0; i < 8; i++) {
    int c = tid + i * 256;
    int r = c >> 6, ql = c & 63;
    gld16(&W[(size_t)(n0 + r) * 512 + swz(ql, r) * 8], &Ws[(c & ~63) * 8]);
  }
  __syncthreads();
  const int rA = wm * 16 + lr, rB = wn * 16 + lr;
  floatx4 ac[4];
#pragma unroll
  for (int j = 0; j < 4; j++) ac[j] = (floatx4){0.f, 0.f, 0.f, 0.f};
#pragma unroll
  for (int t = 0; t < 4; t++) {
#pragma unroll
    for (int j = 0; j < 4; j++) {
      int q = ((j * 128 + t * 32) >> 3) + lk;
      short8 av = *(const short8*)&As[rA * 512 + swz(q, rA) * 8];
      short8 bv = *(const short8*)&Ws[rB * 512 + swz(q, rB) * 8];
      ac[j] = __builtin_amdgcn_mfma_f32_16x16x32_bf16(av, bv, ac[j], 0, 0, 0);
    }
  }
  floatx4 acc = (ac[0] + ac[1]) + (ac[2] + ac[3]);
  int n = n0 + wn * 16 + lr;
  float bn = bias[n];
  // C/D layout (m89-verified): col = lane&15, row = (lane>>4)*4 + reg
#pragma unroll
  for (int r = 0; r < 4; r++) {
    int m = m0 + wm * 16 + lk * 4 + r;
    C[(size_t)m * 512 + n] = f2bf(elu1(acc[r] + bn));
  }
}

// ---- expert GEMM v3: 64x32 block tile, BK=128, kz=4; R7 dbuf e-loop --------
// grid (16 n, 8 m, 4 kz) = 512 blocks, 34 KB LDS -> 2 blocks/CU, 8 waves/CU.
// Each wave: two 16x16 M-stacked tiles sharing one B-fragment stream; A
// fragments hoisted to registers once (A invariant across experts) -> in-loop
// LDS reads are B-only (4 reads feed 8 MFMAs per expert).
template <int FROMP>
__global__ __launch_bounds__(256) void expert_gemm(
    const unsigned short* __restrict__ A,   // [512,512] bf16 (FROMP=0)
    const float* __restrict__ Pin,          // [4][512][512] (FROMP=1)
    const unsigned short* __restrict__ Wb,  // [E*512,512] bf16 alpha bank
    const float* __restrict__ g,            // [512,8] gates
    const float* __restrict__ beta,         // [E*512] fp32
    float* __restrict__ Pout) {             // [4][512][512] fp32 partials
  __shared__ unsigned short As[64 * 128];     // 16 KB
  __shared__ unsigned short Ws[2][32 * 128];  // 2 x 8 KB
  __shared__ float gl[64 * 8];                // 2 KB gates cache
  const int tid = threadIdx.x;
  const int wave = tid >> 6, lane = tid & 63;
  const int wm = wave >> 1, wn = wave & 1;
  const int lr = lane & 15, lk = lane >> 4;
  const int n0 = blockIdx.x * 32, m0 = blockIdx.y * 64;
  const int kz = blockIdx.z, kbeg = kz * 128;

  // ---- A panel staging (64 rows x 128 cols = 1024 chunks, 4/thread) ----
  if (FROMP) {
#pragma unroll
    for (int i = 0; i < 4; i++) {
      int c = tid + i * 256;
      int r = c >> 4, q = c & 15;
      const float* p = Pin + (size_t)(m0 + r) * 512 + kbeg + q * 8;
      float s0 = 0.f, s1 = 0.f, s2 = 0.f, s3 = 0.f;
      float s4 = 0.f, s5 = 0.f, s6 = 0.f, s7 = 0.f;
#pragma unroll
      for (int z = 0; z < 4; z++) {
        const float* pz = p + (size_t)z * (Bq * Hq);
        float4 a = *(const float4*)pz;
        float4 b = *(const float4*)(pz + 4);
        s0 += a.x; s1 += a.y; s2 += a.z; s3 += a.w;
        s4 += b.x; s5 += b.y; s6 += b.z; s7 += b.w;
      }
      short8 o;
      o[0] = (short)f2bf(elu1(s0)); o[1] = (short)f2bf(elu1(s1));
      o[2] = (short)f2bf(elu1(s2)); o[3] = (short)f2bf(elu1(s3));
      o[4] = (short)f2bf(elu1(s4)); o[5] = (short)f2bf(elu1(s5));
      o[6] = (short)f2bf(elu1(s6)); o[7] = (short)f2bf(elu1(s7));
      *(short8*)&As[(r * 16 + swz(q, r)) * 8] = o;
    }
  } else {
#pragma unroll
    for (int i = 0; i < 4; i++) {
      int c = tid + i * 256;
      int r = c >> 4, ql = c & 15;
      gld16(&A[(size_t)(m0 + r) * 512 + kbeg + swz(ql, r) * 8],
            &As[(c & ~63) * 8]);
    }
  }
  // gates for the block's 64 rows -> LDS
  if (tid < 128)
    ((float4*)gl)[tid] = ((const float4*)(g + (size_t)m0 * 8))[tid];

  // W panel staging (32 rows x 128 cols = 512 chunks, 2/thread)
  auto stageW = [&](int e, int b) {
    const unsigned short* Wp = Wb + ((size_t)e * 512 + n0) * 512 + kbeg;
#pragma unroll
    for (int i = 0; i < 2; i++) {
      int c = tid + i * 256;
      int r = c >> 4, ql = c & 15;
      gld16(&Wp[(size_t)r * 512 + swz(ql, r) * 8], &Ws[b][(c & ~63) * 8]);
    }
  };
  stageW(0, 0);

  short8 af[2][4];  // hoisted A fragments: [m-subtile][kk-step]
  floatx4 fin[2] = {{0.f, 0.f, 0.f, 0.f}, {0.f, 0.f, 0.f, 0.f}};
  const int rB = wn * 16 + lr;

#pragma unroll
  for (int e = 0; e < 8; e++) {
    __syncthreads();                          // W[e] (and at e=0, A) ready
    if (e < 7) stageW(e + 1, (e + 1) & 1);    // prefetch overlaps MFMA
    if (e == 0) {
#pragma unroll
      for (int s = 0; s < 2; s++) {
        int rA = s * 32 + wm * 16 + lr;
#pragma unroll
        for (int t = 0; t < 4; t++)
          af[s][t] = *(const short8*)&As[(rA * 16 + swz(t * 4 + lk, rA)) * 8];
      }
    }
    const unsigned short* wb = Ws[e & 1];
    floatx4 acc[2] = {{0.f, 0.f, 0.f, 0.f}, {0.f, 0.f, 0.f, 0.f}};
#pragma unroll
    for (int t = 0; t < 4; t++) {
      short8 bv = *(const short8*)&wb[(rB * 16 + swz(t * 4 + lk, rB)) * 8];
      acc[0] = __builtin_amdgcn_mfma_f32_16x16x32_bf16(af[0][t], bv, acc[0],
                                                       0, 0, 0);
      acc[1] = __builtin_amdgcn_mfma_f32_16x16x32_bf16(af[1][t], bv, acc[1],
                                                       0, 0, 0);
    }
#pragma unroll
    for (int s = 0; s < 2; s++) {
#pragma unroll
      for (int r = 0; r < 4; r++) {
        float ge = gl[(s * 32 + wm * 16 + lk * 4 + r) * 8 + e];
        fin[s][r] += ge * acc[s][r];
      }
    }
  }

  // epilogue: kz==0 folds gate-blended beta; write fp32 partial
  float* Po = Pout + (size_t)kz * Bq * Hq;
  int n = n0 + wn * 16 + lr;
#pragma unroll
  for (int s = 0; s < 2; s++) {
#pragma unroll
    for (int r = 0; r < 4; r++) {
      int row = s * 32 + wm * 16 + lk * 4 + r;
      float v = fin[s][r];
      if (kz == 0) {
#pragma unroll
        for (int e = 0; e < 8; e++)
          v += gl[row * 8 + e] * beta[e * 512 + n];
      }
      Po[(size_t)(m0 + row) * 512 + n] = v;
    }
  }
}

// ---------------- gate logits + softmax (one wave per sample) ----------------
__global__ __launch_bounds__(64) void gate_kernel(
    const unsigned short* __restrict__ G1,  // [B,H] bf16
    const float* __restrict__ gw2,          // [E,H]
    const float* __restrict__ gb2,          // [E]
    float* __restrict__ g) {                // [B,E]
  int b = blockIdx.x;
  int lane = threadIdx.x;
  float xv[8];
#pragma unroll
  for (int t = 0; t < 8; t++) xv[t] = bf2f(G1[(size_t)b * Hq + t * 64 + lane]);
  float le[Eq];
#pragma unroll
  for (int e = 0; e < Eq; e++) {
    float p = 0.f;
#pragma unroll
    for (int t = 0; t < 8; t++)
      p += xv[t] * gw2[(size_t)e * Hq + t * 64 + lane];
#pragma unroll
    for (int o = 32; o > 0; o >>= 1) p += __shfl_xor(p, o);
    le[e] = p + gb2[e];
  }
  float m = le[0];
#pragma unroll
  for (int e = 1; e < Eq; e++) m = fmaxf(m, le[e]);
  float s = 0.f;
#pragma unroll
  for (int e = 0; e < Eq; e++) {
    le[e] = __expf(le[e] - m);
    s += le[e];
  }
  float inv = 1.f / s;
  if (lane == 0) {
#pragma unroll
    for (int e = 0; e < Eq; e++) g[(size_t)b * Eq + e] = le[e] * inv;
  }
}

// ---------- final reduce: out = sum_z P[z] (beta already folded) ------------
__global__ __launch_bounds__(256) void reduce_final(
    const float* __restrict__ P, float* __restrict__ outf) {
  int idx = blockIdx.x * 256 + threadIdx.x;  // over B*H/4
  float4 s = {0.f, 0.f, 0.f, 0.f};
#pragma unroll
  for (int z = 0; z < 4; z++) {
    float4 v = ((const float4*)(P + (size_t)z * Bq * Hq))[idx];
    s.x += v.x; s.y += v.y; s.z += v.z; s.w += v.w;
  }
  ((float4*)outf)[idx] = s;
}

extern "C" void kernel_launch(void* const* d_in, const int* in_sizes, int n_in,
                              void* d_out, int out_size, void* d_ws,
                              size_t ws_size, hipStream_t stream) {
  const float* x = (const float*)d_in[0];
  const float* gw0 = (const float*)d_in[1];
  const float* gb0 = (const float*)d_in[2];
  const float* gw1 = (const float*)d_in[3];
  const float* gb1 = (const float*)d_in[4];
  const float* gw2 = (const float*)d_in[5];
  const float* gb2 = (const float*)d_in[6];
  const float* alpha0 = (const float*)d_in[7];
  const float* beta0 = (const float*)d_in[8];
  const float* alpha1 = (const float*)d_in[9];
  const float* beta1 = (const float*)d_in[10];
  const float* alpha2 = (const float*)d_in[11];
  const float* beta2 = (const float*)d_in[12];
  float* out = (float*)d_out;

  char* ws = (char*)d_ws;
  auto alloc = [&](size_t bytes) {
    char* p = ws;
    ws += (bytes + 255) & ~(size_t)255;
    return p;
  };
  unsigned short* xb = (unsigned short*)alloc((size_t)Bq * Fq * 2);
  unsigned short* gw0b = (unsigned short*)alloc((size_t)Hq * Fq * 2);
  unsigned short* gw1b = (unsigned short*)alloc((size_t)Hq * Hq * 2);
  unsigned short* a0b = (unsigned short*)alloc((size_t)Eq * Hq * Fq * 2);
  unsigned short* a1b = (unsigned short*)alloc((size_t)Eq * Hq * Hq * 2);
  unsigned short* a2b = (unsigned short*)alloc((size_t)Eq * Oq * Hq * 2);
  unsigned short* G0b = (unsigned short*)alloc((size_t)Bq * Hq * 2);
  unsigned short* G1b = (unsigned short*)alloc((size_t)Bq * Hq * 2);
  float* gates = (float*)alloc((size_t)Bq * Eq * 4);
  float* P1 = (float*)alloc((size_t)4 * Bq * Hq * 4);
  float* P2 = (float*)alloc((size_t)4 * Bq * Hq * 4);

  // 1) all fp32->bf16 converts in one launch
  {
    int nb = (Eq * Hq * Fq) / 4, ns = (Bq * Fq) / 4;
    int total = 3 * nb + 3 * ns;
    cvt6_kernel<<<(total + 255) / 256, 256, 0, stream>>>(
        alpha0, alpha1, alpha2, a0b, a1b, a2b, x, gw0, gw1, xb, gw0b, gw1b,
        nb, ns);
  }

  // 2) gating MLP: single-barrier 32x32 tiles, 256 blocks each
  dim3 gg(16, 16);
  gating_gemm<<<gg, 256, 0, stream>>>(xb, gw0b, gb0, G0b);
  gating_gemm<<<gg, 256, 0, stream>>>(G0b, gw1b, gb1, G1b);

  // 3) gate logits + softmax
  gate_kernel<<<Bq, 64, 0, stream>>>(G1b, gw2, gb2, gates);

  // 4) experts: 64x32 blocks, A-frag hoist, dbuf W prefetch; final reduce
  dim3 ge(16, 8, 4);
  expert_gemm<0><<<ge, 256, 0, stream>>>(xb, nullptr, a0b, gates, beta0, P1);
  expert_gemm<1><<<ge, 256, 0, stream>>>(nullptr, P1, a1b, gates, beta1, P2);
  expert_gemm<1><<<ge, 256, 0, stream>>>(nullptr, P2, a2b, gates, beta2, P1);
  reduce_final<<<(Bq * Hq / 4) / 256, 256, 0, stream>>>(P1, out);
}

// Round 10
// 136.068 us; speedup vs baseline: 1.0502x; 1.0227x over previous
//
#include <hip/hip_runtime.h>
#include <hip/hip_bf16.h>
#include <math.h>

// Problem constants (B,F,H,E,O) = (512,512,512,8,512)
enum { Bq = 512, Fq = 512, Hq = 512, Eq = 8, Oq = 512 };

typedef __attribute__((ext_vector_type(8))) short short8;
typedef __attribute__((ext_vector_type(4))) float floatx4;

static __device__ __forceinline__ unsigned short f2bf(float f) {
  unsigned u = __float_as_uint(f);
  u += 0x7fffu + ((u >> 16) & 1u);
  return (unsigned short)(u >> 16);
}
static __device__ __forceinline__ float bf2f(unsigned short h) {
  return __uint_as_float(((unsigned)h) << 16);
}
static __device__ __forceinline__ float elu1(float v) {
  return v > 0.f ? v : (__expf(v) - 1.f);
}

// async global->LDS 16B copy (wave-uniform LDS base + lane*16 scatter)
typedef __attribute__((address_space(1))) const unsigned int gu32;
typedef __attribute__((address_space(3))) unsigned int lu32;
static __device__ __forceinline__ void gld16(const unsigned short* g,
                                             unsigned short* l) {
  __builtin_amdgcn_global_load_lds((gu32*)g, (lu32*)l, 16, 0, 0);
}

// XOR swizzle on 16B chunks (fragment-read conflicts -> 2-way = free).
static __device__ __forceinline__ int swz(int q, int r) {
  return (q & ~7) | ((q ^ r) & 7);
}

// one 256-thread block converts 256 float4 (1024 elems) fp32->bf16
static __device__ __forceinline__ void cvt_chunk(const float* __restrict__ src,
                                                 unsigned short* __restrict__ dst,
                                                 int chunk, int tid) {
  int j = chunk * 256 + tid;
  float4 v = ((const float4*)src)[j];
  ushort4 o;
  o.x = f2bf(v.x); o.y = f2bf(v.y); o.z = f2bf(v.z); o.w = f2bf(v.w);
  *(ushort4*)(dst + 4 * (size_t)j) = o;
}

// ---------- small cvt: x, gw0, gw1 (65536 float4 each, 768 blocks) ----------
__global__ __launch_bounds__(256) void cvt_small(
    const float* __restrict__ s0, const float* __restrict__ s1,
    const float* __restrict__ s2, unsigned short* __restrict__ d0,
    unsigned short* __restrict__ d1, unsigned short* __restrict__ d2) {
  int blk = blockIdx.x;
  int seg = blk >> 8, c = blk & 255;
  const float* s = (seg == 0) ? s0 : (seg == 1) ? s1 : s2;
  unsigned short* d = (seg == 0) ? d0 : (seg == 1) ? d1 : d2;
  cvt_chunk(s, d, c, threadIdx.x);
}

// --- gating GEMM (blocks 0..255) + alpha cvt (blocks 256..2303) fused -------
// gemm: 32x32 tile, BK=512 (full K), one barrier. cvt: 2048 chunk-blocks
// converting one 8 MB alpha bank, hidden under the latency-bound GEMM.
__global__ __launch_bounds__(256) void gating_cvt(
    const unsigned short* __restrict__ A, const unsigned short* __restrict__ W,
    const float* __restrict__ bias, unsigned short* __restrict__ C,
    const float* __restrict__ asrc, unsigned short* __restrict__ adst) {
  const int blk = blockIdx.x, tid = threadIdx.x;
  if (blk >= 256) {
    cvt_chunk(asrc, adst, blk - 256, tid);
    return;
  }
  __shared__ unsigned short As[32 * 512];
  __shared__ unsigned short Ws[32 * 512];
  const int wave = tid >> 6, lane = tid & 63;
  const int wm = wave >> 1, wn = wave & 1;
  const int lr = lane & 15, lk = lane >> 4;
  const int m0 = (blk >> 4) * 32, n0 = (blk & 15) * 32;
#pragma unroll
  for (int i = 0; i < 8; i++) {
    int c = tid + i * 256;
    int r = c >> 6, ql = c & 63;
    gld16(&A[(size_t)(m0 + r) * 512 + swz(ql, r) * 8], &As[(c & ~63) * 8]);
  }
#pragma unroll
  for (int i = 0; i < 8; i++) {
    int c = tid + i * 256;
    int r = c >> 6, ql = c & 63;
    gld16(&W[(size_t)(n0 + r) * 512 + swz(ql, r) * 8], &Ws[(c & ~63) * 8]);
  }
  __syncthreads();
  const int rA = wm * 16 + lr, rB = wn * 16 + lr;
  floatx4 ac[4];
#pragma unroll
  for (int j = 0; j < 4; j++) ac[j] = (floatx4){0.f, 0.f, 0.f, 0.f};
#pragma unroll
  for (int t = 0; t < 4; t++) {
#pragma unroll
    for (int j = 0; j < 4; j++) {
      int q = ((j * 128 + t * 32) >> 3) + lk;
      short8 av = *(const short8*)&As[rA * 512 + swz(q, rA) * 8];
      short8 bv = *(const short8*)&Ws[rB * 512 + swz(q, rB) * 8];
      ac[j] = __builtin_amdgcn_mfma_f32_16x16x32_bf16(av, bv, ac[j], 0, 0, 0);
    }
  }
  floatx4 acc = (ac[0] + ac[1]) + (ac[2] + ac[3]);
  int n = n0 + wn * 16 + lr;
  float bn = bias[n];
  // C/D layout (m89-verified): col = lane&15, row = (lane>>4)*4 + reg
#pragma unroll
  for (int r = 0; r < 4; r++) {
    int m = m0 + wm * 16 + lk * 4 + r;
    C[(size_t)m * 512 + n] = f2bf(elu1(acc[r] + bn));
  }
}

// --- gate softmax (blocks 0..127, 4 samples/block) + out-zero (128..383)
//     + alpha2 cvt (blocks 384..2431) ---------------------------------------
__global__ __launch_bounds__(256) void gate_fused(
    const unsigned short* __restrict__ G1,  // [B,H] bf16
    const float* __restrict__ gw2,          // [E,H]
    const float* __restrict__ gb2,          // [E]
    float* __restrict__ g,                  // [B,E]
    const float* __restrict__ asrc, unsigned short* __restrict__ adst,
    float* __restrict__ outz) {
  const int blk = blockIdx.x, tid = threadIdx.x;
  if (blk >= 384) {
    cvt_chunk(asrc, adst, blk - 384, tid);
    return;
  }
  if (blk >= 128) {
    ((float4*)outz)[(blk - 128) * 256 + tid] = (float4){0.f, 0.f, 0.f, 0.f};
    return;
  }
  const int wave = tid >> 6, lane = tid & 63;
  const int b = blk * 4 + wave;
  float xv[8];
#pragma unroll
  for (int t = 0; t < 8; t++) xv[t] = bf2f(G1[(size_t)b * Hq + t * 64 + lane]);
  float le[Eq];
#pragma unroll
  for (int e = 0; e < Eq; e++) {
    float p = 0.f;
#pragma unroll
    for (int t = 0; t < 8; t++)
      p += xv[t] * gw2[(size_t)e * Hq + t * 64 + lane];
#pragma unroll
    for (int o = 32; o > 0; o >>= 1) p += __shfl_xor(p, o);
    le[e] = p + gb2[e];
  }
  float m = le[0];
#pragma unroll
  for (int e = 1; e < Eq; e++) m = fmaxf(m, le[e]);
  float s = 0.f;
#pragma unroll
  for (int e = 0; e < Eq; e++) {
    le[e] = __expf(le[e] - m);
    s += le[e];
  }
  float inv = 1.f / s;
  if (lane == 0) {
#pragma unroll
    for (int e = 0; e < Eq; e++) g[(size_t)b * Eq + e] = le[e] * inv;
  }
}

// ---- expert GEMM (R7 shape): 32x32 tile, all 8 experts/block, dbuf W -------
// grid (16 n, 16 m, 2 kz) = 512 blocks, 48 KB LDS -> 3 blocks/CU.
// FROMP: A-panel = elu(Pin[0]+Pin[1]) staged via VALU (fused reduce).
// ATOMIC: epilogue atomicAdds into Out (pre-zeroed) instead of writing Pout.
template <int FROMP, int ATOMIC>
__global__ __launch_bounds__(256) void expert_gemm(
    const unsigned short* __restrict__ A,   // [512,512] bf16 (FROMP=0)
    const float* __restrict__ Pin,          // [2][512][512] (FROMP=1)
    const unsigned short* __restrict__ Wb,  // [E*512,512] bf16 alpha bank
    const float* __restrict__ g,            // [512,8] gates
    const float* __restrict__ beta,         // [E*512] fp32
    float* __restrict__ Pout) {             // [2][512][512] or out[512][512]
  __shared__ unsigned short As[32 * 256];      // 16 KB
  __shared__ unsigned short Ws[2][32 * 256];   // 2 x 16 KB
  const int tid = threadIdx.x;
  const int wave = tid >> 6, lane = tid & 63;
  const int wm = wave >> 1, wn = wave & 1;
  const int lr = lane & 15, lk = lane >> 4;
  const int m0 = blockIdx.y * 32, n0 = blockIdx.x * 32;
  const int kz = blockIdx.z, kbeg = kz * 256;

  // stage A panel (32x256): 1024 chunks, 4 per thread
  if (FROMP) {
#pragma unroll
    for (int i = 0; i < 4; i++) {
      int c = tid + i * 256;
      int r = c >> 5, q = c & 31;
      const float* p0 = Pin + (size_t)(m0 + r) * 512 + kbeg + q * 8;
      const float* p1 = p0 + (size_t)Bq * Hq;
      float4 x0 = *(const float4*)p0, x1 = *(const float4*)(p0 + 4);
      float4 y0 = *(const float4*)p1, y1 = *(const float4*)(p1 + 4);
      short8 o;
      o[0] = (short)f2bf(elu1(x0.x + y0.x));
      o[1] = (short)f2bf(elu1(x0.y + y0.y));
      o[2] = (short)f2bf(elu1(x0.z + y0.z));
      o[3] = (short)f2bf(elu1(x0.w + y0.w));
      o[4] = (short)f2bf(elu1(x1.x + y1.x));
      o[5] = (short)f2bf(elu1(x1.y + y1.y));
      o[6] = (short)f2bf(elu1(x1.z + y1.z));
      o[7] = (short)f2bf(elu1(x1.w + y1.w));
      *(short8*)&As[(r * 32 + swz(q, r)) * 8] = o;
    }
  } else {
#pragma unroll
    for (int i = 0; i < 4; i++) {
      int c = tid + i * 256;
      int r = c >> 5, ql = c & 31;
      gld16(&A[(size_t)(m0 + r) * 512 + kbeg + swz(ql, r) * 8],
            &As[(c & ~63) * 8]);
    }
  }
  // stage W panel for expert 0 into buffer 0
  auto stageW = [&](int e, int b) {
    const unsigned short* Wp = Wb + ((size_t)e * 512 + n0) * 512 + kbeg;
#pragma unroll
    for (int i = 0; i < 4; i++) {
      int c = tid + i * 256;
      int r = c >> 5, ql = c & 31;
      gld16(&Wp[(size_t)r * 512 + swz(ql, r) * 8], &Ws[b][(c & ~63) * 8]);
    }
  };
  stageW(0, 0);
  // gates for this lane's 4 output rows
  float g8[4][8];
#pragma unroll
  for (int r = 0; r < 4; r++) {
    int m = m0 + wm * 16 + lk * 4 + r;
    float4 ga = *(const float4*)&g[(size_t)m * 8];
    float4 gb = *(const float4*)&g[(size_t)m * 8 + 4];
    g8[r][0] = ga.x; g8[r][1] = ga.y; g8[r][2] = ga.z; g8[r][3] = ga.w;
    g8[r][4] = gb.x; g8[r][5] = gb.y; g8[r][6] = gb.z; g8[r][7] = gb.w;
  }

  const int rA = wm * 16 + lr, rB = wn * 16 + lr;
  floatx4 fin = {0.f, 0.f, 0.f, 0.f};
#pragma unroll
  for (int e = 0; e < 8; e++) {
    __syncthreads();                        // A + W[e] ready; fences reuse
    if (e < 7) stageW(e + 1, (e + 1) & 1);  // prefetch overlaps MFMA
    const unsigned short* wb = Ws[e & 1];
    floatx4 c0 = {0.f, 0.f, 0.f, 0.f}, c1 = {0.f, 0.f, 0.f, 0.f};
#pragma unroll
    for (int s = 0; s < 8; s++) {
      int q = s * 4 + lk;
      short8 av = *(const short8*)&As[rA * 256 + swz(q, rA) * 8];
      short8 bv = *(const short8*)&wb[rB * 256 + swz(q, rB) * 8];
      if (s & 1)
        c1 = __builtin_amdgcn_mfma_f32_16x16x32_bf16(av, bv, c1, 0, 0, 0);
      else
        c0 = __builtin_amdgcn_mfma_f32_16x16x32_bf16(av, bv, c0, 0, 0, 0);
    }
    floatx4 ae = c0 + c1;
#pragma unroll
    for (int r = 0; r < 4; r++) fin[r] += g8[r][e] * ae[r];
  }

  int n = n0 + wn * 16 + lr;
  if (kz == 0) {  // fold gate-blended beta into the kz=0 partial
    float bv[8];
#pragma unroll
    for (int e = 0; e < 8; e++) bv[e] = beta[e * 512 + n];
#pragma unroll
    for (int r = 0; r < 4; r++) {
      float bs = 0.f;
#pragma unroll
      for (int e = 0; e < 8; e++) bs += g8[r][e] * bv[e];
      fin[r] += bs;
    }
  }
  if (ATOMIC) {
#pragma unroll
    for (int r = 0; r < 4; r++) {
      int m = m0 + wm * 16 + lk * 4 + r;
      atomicAdd(&Pout[(size_t)m * 512 + n], fin[r]);
    }
  } else {
    float* Po = Pout + (size_t)kz * Bq * Hq;
#pragma unroll
    for (int r = 0; r < 4; r++) {
      int m = m0 + wm * 16 + lk * 4 + r;
      Po[(size_t)m * 512 + n] = fin[r];
    }
  }
}

extern "C" void kernel_launch(void* const* d_in, const int* in_sizes, int n_in,
                              void* d_out, int out_size, void* d_ws,
                              size_t ws_size, hipStream_t stream) {
  const float* x = (const float*)d_in[0];
  const float* gw0 = (const float*)d_in[1];
  const float* gb0 = (const float*)d_in[2];
  const float* gw1 = (const float*)d_in[3];
  const float* gb1 = (const float*)d_in[4];
  const float* gw2 = (const float*)d_in[5];
  const float* gb2 = (const float*)d_in[6];
  const float* alpha0 = (const float*)d_in[7];
  const float* beta0 = (const float*)d_in[8];
  const float* alpha1 = (const float*)d_in[9];
  const float* beta1 = (const float*)d_in[10];
  const float* alpha2 = (const float*)d_in[11];
  const float* beta2 = (const float*)d_in[12];
  float* out = (float*)d_out;

  char* ws = (char*)d_ws;
  auto alloc = [&](size_t bytes) {
    char* p = ws;
    ws += (bytes + 255) & ~(size_t)255;
    return p;
  };
  unsigned short* xb = (unsigned short*)alloc((size_t)Bq * Fq * 2);
  unsigned short* gw0b = (unsigned short*)alloc((size_t)Hq * Fq * 2);
  unsigned short* gw1b = (unsigned short*)alloc((size_t)Hq * Hq * 2);
  unsigned short* a0b = (unsigned short*)alloc((size_t)Eq * Hq * Fq * 2);
  unsigned short* a1b = (unsigned short*)alloc((size_t)Eq * Hq * Hq * 2);
  unsigned short* a2b = (unsigned short*)alloc((size_t)Eq * Oq * Hq * 2);
  unsigned short* G0b = (unsigned short*)alloc((size_t)Bq * Hq * 2);
  unsigned short* G1b = (unsigned short*)alloc((size_t)Bq * Hq * 2);
  float* gates = (float*)alloc((size_t)Bq * Eq * 4);
  float* P1 = (float*)alloc((size_t)2 * Bq * Hq * 4);
  float* P2 = (float*)alloc((size_t)2 * Bq * Hq * 4);

  // 1) small converts (x, gw0, gw1)
  cvt_small<<<768, 256, 0, stream>>>(x, gw0, gw1, xb, gw0b, gw1b);

  // 2) gating GEMMs with alpha0/alpha1 cvt hidden under them
  gating_cvt<<<2304, 256, 0, stream>>>(xb, gw0b, gb0, G0b, alpha0, a0b);
  gating_cvt<<<2304, 256, 0, stream>>>(G0b, gw1b, gb1, G1b, alpha1, a1b);

  // 3) gate softmax + alpha2 cvt + out zero-init
  gate_fused<<<2432, 256, 0, stream>>>(G1b, gw2, gb2, gates, alpha2, a2b, out);

  // 4) experts (R7 shape); layer 3 atomically accumulates into out
  dim3 ge(16, 16, 2);
  expert_gemm<0, 0><<<ge, 256, 0, stream>>>(xb, nullptr, a0b, gates, beta0, P1);
  expert_gemm<1, 0><<<ge, 256, 0, stream>>>(nullptr, P1, a1b, gates, beta1, P2);
  expert_gemm<1, 1><<<ge, 256, 0, stream>>>(nullptr, P2, a2b, gates, beta2, out);
}